// Round 6
// baseline (293.285 us; speedup 1.0000x reference)
//
#include <hip/hip_runtime.h>
#include <hip/hip_bf16.h>

#define NN 20000
#define EE 320000
#define E4 (EE/4)
#define KK 4
#define FIN 512
#define FHID 256
#define FOUT 128
#define FHD 256
#define NH (2*FOUT+3)   // 259
#define CAP1 1024       // max L1 edges (edges into the 2 targets); expected ~32
#define MS2 128         // max unique slot nodes; expected ~35
#define BCAP 256        // max in-edges per slot node; expected ~45 worst-case

__device__ __forceinline__ float dinvf(int indeg) {
  // reference deg includes the self-loop -> always >= 1
  return rsqrtf((float)(indeg + 1));
}

// K12: scan dst planes for L1 edges; per-k LAST block then dedups slots + builds reg[]
__global__ __launch_bounds__(256) void k12_scan_slots(const int* __restrict__ ei,
                                                      const int* __restrict__ idx,
                                                      int* __restrict__ cnt1,
                                                      int* __restrict__ L1src,
                                                      int* __restrict__ L1sel,
                                                      int* __restrict__ reg,
                                                      int* __restrict__ slotNode,
                                                      int* __restrict__ mslots,
                                                      int* __restrict__ doneA) {
  __shared__ int lastS;
  int k = blockIdx.y;
  int e4 = blockIdx.x * blockDim.x + threadIdx.x;
  int tid = threadIdx.x;
  if (e4 < E4) {
    const int* srcp = ei + (size_t)k * 2 * EE;
    int4 d4 = ((const int4*)(srcp + EE))[e4];
    int t0 = idx[2 * k], t1 = idx[2 * k + 1];
    int ds[4] = {d4.x, d4.y, d4.z, d4.w};
    #pragma unroll
    for (int c = 0; c < 4; c++) {
      if (ds[c] == t0) {
        int p = atomicAdd(&cnt1[k], 1);
        if (p < CAP1) { L1src[k * CAP1 + p] = srcp[e4 * 4 + c]; L1sel[k * CAP1 + p] = 0; }
      }
      if (ds[c] == t1) {
        int p = atomicAdd(&cnt1[k], 1);
        if (p < CAP1) { L1src[k * CAP1 + p] = srcp[e4 * 4 + c]; L1sel[k * CAP1 + p] = 1; }
      }
    }
  }
  // release our writes, then count this block done
  __threadfence();
  if (tid == 0) {
    int old = __hip_atomic_fetch_add(&doneA[k], 1, __ATOMIC_ACQ_REL, __HIP_MEMORY_SCOPE_AGENT);
    lastS = (old == (int)gridDim.x - 1);
  }
  __syncthreads();
  if (!lastS) return;
  __threadfence();  // acquire side
  // ---- tail phase (one block per k): parallel dedup via atomicCAS claim ----
  int* rk = reg + (size_t)k * NN;
  int n = min(cnt1[k], CAP1) + 2;
  for (int i = tid; i < n; i += 256) {
    int node = (i == 0) ? idx[2 * k] : (i == 1) ? idx[2 * k + 1] : L1src[k * CAP1 + i - 2];
    if (atomicCAS(&rk[node], 0, -2) == 0) {   // claim (winner only)
      int s = atomicAdd(&mslots[k], 1);
      if (s < MS2) { slotNode[k * MS2 + s] = node; rk[node] = s + 1; }
    }
  }
}

// K3: scan; if dst is a slot node, append src to that slot's bucket; flag src as deg-needed
__global__ __launch_bounds__(256) void k3_scanL2(const int* __restrict__ ei,
                                                 int* __restrict__ reg,
                                                 int* __restrict__ bcnt,
                                                 int* __restrict__ bucket) {
  int k = blockIdx.y;
  int e4 = blockIdx.x * blockDim.x + threadIdx.x;
  if (e4 >= E4) return;
  const int* srcp = ei + (size_t)k * 2 * EE;
  int4 d4 = ((const int4*)(srcp + EE))[e4];
  int* rk = reg + (size_t)k * NN;
  int ds[4] = {d4.x, d4.y, d4.z, d4.w};
  #pragma unroll
  for (int c = 0; c < 4; c++) {
    int rv = rk[ds[c]];
    if (rv > 0) {
      int s = rv - 1;
      int u = srcp[e4 * 4 + c];
      int p = atomicAdd(&bcnt[k * MS2 + s], 1);
      if (p < BCAP) bucket[((size_t)k * MS2 + s) * BCAP + p] = u;
      if (rk[u] == 0) rk[u] = -1;  // benign race: both writers store -1
    }
  }
}

// K4: scan; count in-degree only for flagged/registered nodes (~11K atomics total)
__global__ __launch_bounds__(256) void k4_deg(const int* __restrict__ ei,
                                              const int* __restrict__ reg,
                                              int* __restrict__ deg) {
  int k = blockIdx.y;
  int e4 = blockIdx.x * blockDim.x + threadIdx.x;
  if (e4 >= E4) return;
  const int* dstp = ei + (size_t)k * 2 * EE + EE;
  int4 d4 = ((const int4*)dstp)[e4];
  const int* rk = reg + (size_t)k * NN;
  int ds[4] = {d4.x, d4.y, d4.z, d4.w};
  #pragma unroll
  for (int c = 0; c < 4; c++) {
    if (rk[ds[c]] != 0) atomicAdd(&deg[k * NN + ds[c]], 1);
  }
}

// K56: per slot (1024 thr): gather + GEMV1 + relu + GEMV2 -> HW2; per-k LAST block decodes
__global__ __launch_bounds__(1024) void k56_mlp_decode(
    const int* __restrict__ slotNode, const int* __restrict__ mslots,
    const int* __restrict__ bcnt, const int* __restrict__ bucket,
    const int* __restrict__ deg, const float* __restrict__ x,
    const float* __restrict__ W1, const float* __restrict__ b1,
    const float* __restrict__ W2, float* __restrict__ HW2,
    const float* __restrict__ b2, const int* __restrict__ cnt1,
    const int* __restrict__ L1src, const int* __restrict__ L1sel,
    const int* __restrict__ idx, const int* __restrict__ reg,
    const float* __restrict__ value, const float* __restrict__ Wd,
    const float* __restrict__ bd, const float* __restrict__ Wp,
    const float* __restrict__ bp, float* __restrict__ out,
    int* __restrict__ doneB) {
  __shared__ float aggS[FIN];       // 2 KB
  __shared__ float gtmp[FIN];       // 2 KB
  __shared__ float part[4][FHID];   // 4 KB
  __shared__ float hrow[FHID];      // 1 KB
  __shared__ float part2[8][FOUT];  // 4 KB
  __shared__ int   uS[BCAP];        // 1 KB
  __shared__ float duS[BCAP];       // 1 KB
  __shared__ float hD[NH + 1];      // 1 KB
  __shared__ float oD[FHD];         // 1 KB
  __shared__ float pd[4][FHD];      // 4 KB
  __shared__ float red[4];
  __shared__ int lastS;
  int k = blockIdx.y, s = blockIdx.x;
  int tid = threadIdx.x;
  if (s < mslots[k]) {
    int node = slotNode[k * MS2 + s];
    int nb = min(bcnt[k * MS2 + s], BCAP);
    const int* bk = bucket + ((size_t)k * MS2 + s) * BCAP;
    for (int e = tid; e < nb; e += 1024) {
      int u = bk[e];
      uS[e] = u;
      duS[e] = dinvf(deg[k * NN + u]);
    }
    __syncthreads();
    float dn = dinvf(deg[k * NN + node]);
    // gather: (half, f) decomposition; x-row loads independent, coalesced
    int f = tid & (FIN - 1), half = tid >> 9;
    float a = (half == 0) ? dn * x[(size_t)node * FIN + f] : 0.f;
    for (int e = half; e < nb; e += 2) a += duS[e] * x[(size_t)uS[e] * FIN + f];
    if (half == 1) gtmp[f] = a;
    __syncthreads();
    if (half == 0) aggS[f] = dn * (a + gtmp[f]);
    __syncthreads();
    // GEMV1: kk split over 4 quarter-blocks
    {
      int q = tid >> 8, j = tid & (FHID - 1);
      float acc = 0.f;
      const float* w1p = W1 + (size_t)(q * 128) * FHID + j;
      const float* ap = aggS + q * 128;
      #pragma unroll 8
      for (int kk = 0; kk < 128; kk++) acc += ap[kk] * w1p[(size_t)kk * FHID];
      part[q][j] = acc;
    }
    __syncthreads();
    if (tid < FHID) {
      float v = part[0][tid] + part[1][tid] + part[2][tid] + part[3][tid] + b1[tid];
      hrow[tid] = v > 0.f ? v : 0.f;
    }
    __syncthreads();
    // GEMV2: kk split over 8 eighth-blocks
    {
      int p = tid >> 7, j = tid & (FOUT - 1);
      float a2 = 0.f;
      const float* w2p = W2 + (size_t)(p * 32) * FOUT + j;
      const float* hp = hrow + p * 32;
      #pragma unroll 8
      for (int kk = 0; kk < 32; kk++) a2 += hp[kk] * w2p[(size_t)kk * FOUT];
      part2[p][j] = a2;
    }
    __syncthreads();
    if (tid < FOUT) {
      float sv = part2[0][tid] + part2[1][tid] + part2[2][tid] + part2[3][tid] +
                 part2[4][tid] + part2[5][tid] + part2[6][tid] + part2[7][tid];
      HW2[((size_t)k * MS2 + s) * FOUT + tid] = sv;
    }
  }
  // release HW2 writes; count this block done for plane k
  __threadfence();
  if (tid == 0) {
    int old = __hip_atomic_fetch_add(&doneB[k], 1, __ATOMIC_ACQ_REL, __HIP_MEMORY_SCOPE_AGENT);
    lastS = (old == (int)gridDim.x - 1);
  }
  __syncthreads();
  if (!lastS) return;
  __threadfence();  // acquire side
  // ---- decode tail (one block per k), 1024 threads participate ----
  const int* rk = reg + (size_t)k * NN;
  int n1 = min(cnt1[k], CAP1);
  if (tid < 256) {
    int tsel = tid >> 7, j = tid & 127;
    int t = idx[2 * k + tsel];
    float dit = dinvf(deg[k * NN + t]);
    int tslot = rk[t] - 1;
    float acc = b2[j] + dit * dit * HW2[((size_t)k * MS2 + tslot) * FOUT + j];
    for (int i = 0; i < n1; i++) {
      if (L1sel[k * CAP1 + i] == tsel) {
        int sn = L1src[k * CAP1 + i];
        float dis = dinvf(deg[k * NN + sn]);
        int sslot = rk[sn] - 1;
        acc += dis * dit * HW2[((size_t)k * MS2 + sslot) * FOUT + j];
      }
    }
    hD[tsel * FOUT + j] = acc;
    if (tid < 3) hD[2 * FOUT + tid] = value[k * 3 + tid];
  }
  __syncthreads();
  // decoder layer 1 (259 -> 256), i-range split over 4 quarter-blocks
  {
    int jj = tid & 255, q = tid >> 8;
    int i0 = q * 65, i1 = min(NH, i0 + 65);
    float a2 = (q == 0) ? bd[jj] : 0.f;
    for (int i = i0; i < i1; i++) a2 += hD[i] * Wd[(size_t)i * FHD + jj];
    pd[q][jj] = a2;
  }
  __syncthreads();
  if (tid < FHD) {
    float v = pd[0][tid] + pd[1][tid] + pd[2][tid] + pd[3][tid];
    oD[tid] = v > 0.f ? v : 0.f;
  }
  __syncthreads();
  if (tid < FHD) {
    float r = oD[tid] * Wp[tid];
    for (int off2 = 32; off2 > 0; off2 >>= 1) r += __shfl_down(r, off2);
    if ((tid & 63) == 0) red[tid >> 6] = r;
  }
  __syncthreads();
  if (tid == 0) {
    float ssum = red[0] + red[1] + red[2] + red[3] + bp[0];
    out[k] = 1.f / (1.f + expf(-ssum));
  }
}

extern "C" void kernel_launch(void* const* d_in, const int* in_sizes, int n_in,
                              void* d_out, int out_size, void* d_ws, size_t ws_size,
                              hipStream_t stream) {
  const float* x     = (const float*)d_in[0];
  const int*   ei    = (const int*)d_in[1];
  const float* value = (const float*)d_in[2];
  const int*   idx   = (const int*)d_in[3];
  const float* W1    = (const float*)d_in[4];
  const float* b1    = (const float*)d_in[5];
  const float* W2    = (const float*)d_in[6];
  const float* b2    = (const float*)d_in[7];
  const float* Wd    = (const float*)d_in[8];
  const float* bd    = (const float*)d_in[9];
  const float* Wp    = (const float*)d_in[10];
  const float* bp    = (const float*)d_in[11];
  float* out = (float*)d_out;

  char* ws = (char*)d_ws;
  size_t off = 0;
  auto alloc = [&](size_t bytes) -> void* {
    void* p = ws + off;
    off = (off + bytes + 255) & ~(size_t)255;
    return p;
  };
  // --- zeroed region (one memset): reg, deg, bcnt, cnt1, mslots, doneA, doneB ---
  int* reg   = (int*)alloc((size_t)(2 * KK * NN + KK * MS2 + 4 * KK) * sizeof(int));
  int* deg   = reg + KK * NN;
  int* bcnt  = deg + KK * NN;
  int* cnt1  = bcnt + KK * MS2;
  int* mslots = cnt1 + KK;
  int* doneA = mslots + KK;
  int* doneB = doneA + KK;
  size_t zbytes = (size_t)(2 * KK * NN + KK * MS2 + 4 * KK) * sizeof(int);
  // --- non-zeroed scratch ---
  int* L1src = (int*)alloc((size_t)KK * CAP1 * sizeof(int));
  int* L1sel = (int*)alloc((size_t)KK * CAP1 * sizeof(int));
  int* slotNode = (int*)alloc((size_t)KK * MS2 * sizeof(int));
  int* bucket = (int*)alloc((size_t)KK * MS2 * BCAP * sizeof(int));
  float* HW2 = (float*)alloc((size_t)KK * MS2 * FOUT * sizeof(float));
  (void)ws_size; (void)in_sizes; (void)n_in; (void)out_size;

  hipMemsetAsync(reg, 0, zbytes, stream);

  dim3 escan((E4 + 255) / 256, KK);
  k12_scan_slots<<<escan, 256, 0, stream>>>(ei, idx, cnt1, L1src, L1sel,
                                            reg, slotNode, mslots, doneA);
  k3_scanL2<<<escan, 256, 0, stream>>>(ei, reg, bcnt, bucket);
  k4_deg<<<escan, 256, 0, stream>>>(ei, reg, deg);
  k56_mlp_decode<<<dim3(MS2, KK), 1024, 0, stream>>>(
      slotNode, mslots, bcnt, bucket, deg, x, W1, b1, W2, HW2,
      b2, cnt1, L1src, L1sel, idx, reg, value, Wd, bd, Wp, bp, out, doneB);
}

// Round 7
// 68.675 us; speedup vs baseline: 4.2706x; 4.2706x over previous
//
#include <hip/hip_runtime.h>
#include <hip/hip_bf16.h>

#define NN 20000
#define EE 320000
#define E4 (EE/4)
#define KK 4
#define FIN 512
#define FHID 256
#define FOUT 128
#define FHD 256
#define NH (2*FOUT+3)   // 259
#define CAP1 1024       // max L1 edges (edges into the 2 targets); expected ~32
#define MS2 128         // max unique slot nodes; expected ~35
#define BCAP 256        // max in-edges per slot node; expected ~45 worst-case

__device__ __forceinline__ float dinvf(int indeg) {
  // reference deg includes the self-loop -> always >= 1
  return rsqrtf((float)(indeg + 1));
}

// KZ: zero the counter/flag region (642 KB). Runtime fillBuffer took 40µs; this takes ~2.
__global__ __launch_bounds__(256) void kz_zero(int4* __restrict__ p, int n4) {
  int i = blockIdx.x * 256 + threadIdx.x;
  if (i < n4) p[i] = make_int4(0, 0, 0, 0);
}

// K1: scan dst planes; collect edges whose dst is a target (L1 list)
__global__ __launch_bounds__(256) void k1_scanL1(const int* __restrict__ ei,
                                                 const int* __restrict__ idx,
                                                 int* __restrict__ cnt1,
                                                 int* __restrict__ L1src,
                                                 int* __restrict__ L1sel) {
  int k = blockIdx.y;
  int e4 = blockIdx.x * blockDim.x + threadIdx.x;
  if (e4 >= E4) return;
  const int* srcp = ei + (size_t)k * 2 * EE;
  int4 d4 = ((const int4*)(srcp + EE))[e4];
  int t0 = idx[2 * k], t1 = idx[2 * k + 1];
  int ds[4] = {d4.x, d4.y, d4.z, d4.w};
  #pragma unroll
  for (int c = 0; c < 4; c++) {
    if (ds[c] == t0) {
      int p = atomicAdd(&cnt1[k], 1);
      if (p < CAP1) { L1src[k * CAP1 + p] = srcp[e4 * 4 + c]; L1sel[k * CAP1 + p] = 0; }
    }
    if (ds[c] == t1) {
      int p = atomicAdd(&cnt1[k], 1);
      if (p < CAP1) { L1src[k * CAP1 + p] = srcp[e4 * 4 + c]; L1sel[k * CAP1 + p] = 1; }
    }
  }
}

// K2: parallel dedup via atomicCAS claim; slot order is arbitrary (resolved via reg[])
__global__ __launch_bounds__(256) void k2_slots(const int* __restrict__ idx,
                                                const int* __restrict__ cnt1,
                                                const int* __restrict__ L1src,
                                                int* __restrict__ reg,
                                                int* __restrict__ slotNode,
                                                int* __restrict__ mslots) {
  int k = blockIdx.x;
  int tid = threadIdx.x;
  int* rk = reg + (size_t)k * NN;
  int n = min(cnt1[k], CAP1) + 2;
  for (int i = tid; i < n; i += 256) {
    int node = (i == 0) ? idx[2 * k] : (i == 1) ? idx[2 * k + 1] : L1src[k * CAP1 + i - 2];
    if (atomicCAS(&rk[node], 0, -2) == 0) {   // claim (winner only)
      int s = atomicAdd(&mslots[k], 1);
      if (s < MS2) { slotNode[k * MS2 + s] = node; rk[node] = s + 1; }
    }
  }
}

// K3: scan; if dst is a slot node, append src to that slot's bucket; flag src as deg-needed
__global__ __launch_bounds__(256) void k3_scanL2(const int* __restrict__ ei,
                                                 int* __restrict__ reg,
                                                 int* __restrict__ bcnt,
                                                 int* __restrict__ bucket) {
  int k = blockIdx.y;
  int e4 = blockIdx.x * blockDim.x + threadIdx.x;
  if (e4 >= E4) return;
  const int* srcp = ei + (size_t)k * 2 * EE;
  int4 d4 = ((const int4*)(srcp + EE))[e4];
  int* rk = reg + (size_t)k * NN;
  int ds[4] = {d4.x, d4.y, d4.z, d4.w};
  #pragma unroll
  for (int c = 0; c < 4; c++) {
    int rv = rk[ds[c]];
    if (rv > 0) {
      int s = rv - 1;
      int u = srcp[e4 * 4 + c];
      int p = atomicAdd(&bcnt[k * MS2 + s], 1);
      if (p < BCAP) bucket[((size_t)k * MS2 + s) * BCAP + p] = u;
      if (rk[u] == 0) rk[u] = -1;  // benign race: both writers store -1
    }
  }
}

// K4: scan; count in-degree only for flagged/registered nodes (~11K atomics total)
__global__ __launch_bounds__(256) void k4_deg(const int* __restrict__ ei,
                                              const int* __restrict__ reg,
                                              int* __restrict__ deg) {
  int k = blockIdx.y;
  int e4 = blockIdx.x * blockDim.x + threadIdx.x;
  if (e4 >= E4) return;
  const int* dstp = ei + (size_t)k * 2 * EE + EE;
  int4 d4 = ((const int4*)dstp)[e4];
  const int* rk = reg + (size_t)k * NN;
  int ds[4] = {d4.x, d4.y, d4.z, d4.w};
  #pragma unroll
  for (int c = 0; c < 4; c++) {
    if (rk[ds[c]] != 0) atomicAdd(&deg[k * NN + ds[c]], 1);
  }
}

// K5: per slot (1024 thr, 16 waves): agg = dn*(dn*x[s] + sum du*x[u]); GEMV1+relu+GEMV2
__global__ __launch_bounds__(1024) void k5_slotmlp(const int* __restrict__ slotNode,
                                                   const int* __restrict__ mslots,
                                                   const int* __restrict__ bcnt,
                                                   const int* __restrict__ bucket,
                                                   const int* __restrict__ deg,
                                                   const float* __restrict__ x,
                                                   const float* __restrict__ W1,
                                                   const float* __restrict__ b1,
                                                   const float* __restrict__ W2,
                                                   float* __restrict__ HW2) {
  __shared__ float aggS[FIN];       // 2 KB
  __shared__ float gtmp[FIN];       // 2 KB
  __shared__ float part[4][FHID];   // 4 KB
  __shared__ float hrow[FHID];      // 1 KB
  __shared__ float part2[8][FOUT];  // 4 KB
  __shared__ int   uS[BCAP];        // 1 KB
  __shared__ float duS[BCAP];       // 1 KB
  int k = blockIdx.y, s = blockIdx.x;
  if (s >= mslots[k]) return;
  int tid = threadIdx.x;
  int node = slotNode[k * MS2 + s];
  int nb = min(bcnt[k * MS2 + s], BCAP);
  const int* bk = bucket + ((size_t)k * MS2 + s) * BCAP;
  for (int e = tid; e < nb; e += 1024) {
    int u = bk[e];
    uS[e] = u;
    duS[e] = dinvf(deg[k * NN + u]);
  }
  __syncthreads();
  float dn = dinvf(deg[k * NN + node]);
  // gather: (half, f) decomposition; x-row loads independent, coalesced
  int f = tid & (FIN - 1), half = tid >> 9;
  float a = (half == 0) ? dn * x[(size_t)node * FIN + f] : 0.f;
  for (int e = half; e < nb; e += 2) a += duS[e] * x[(size_t)uS[e] * FIN + f];
  if (half == 1) gtmp[f] = a;
  __syncthreads();
  if (half == 0) aggS[f] = dn * (a + gtmp[f]);
  __syncthreads();
  // GEMV1: kk split over 4 quarter-blocks
  {
    int q = tid >> 8, j = tid & (FHID - 1);
    float acc = 0.f;
    const float* w1p = W1 + (size_t)(q * 128) * FHID + j;
    const float* ap = aggS + q * 128;
    #pragma unroll 8
    for (int kk = 0; kk < 128; kk++) acc += ap[kk] * w1p[(size_t)kk * FHID];
    part[q][j] = acc;
  }
  __syncthreads();
  if (tid < FHID) {
    float v = part[0][tid] + part[1][tid] + part[2][tid] + part[3][tid] + b1[tid];
    hrow[tid] = v > 0.f ? v : 0.f;
  }
  __syncthreads();
  // GEMV2: kk split over 8 eighth-blocks
  {
    int p = tid >> 7, j = tid & (FOUT - 1);
    float a2 = 0.f;
    const float* w2p = W2 + (size_t)(p * 32) * FOUT + j;
    const float* hp = hrow + p * 32;
    #pragma unroll 8
    for (int kk = 0; kk < 32; kk++) a2 += hp[kk] * w2p[(size_t)kk * FOUT];
    part2[p][j] = a2;
  }
  __syncthreads();
  if (tid < FOUT) {
    float sv = part2[0][tid] + part2[1][tid] + part2[2][tid] + part2[3][tid] +
               part2[4][tid] + part2[5][tid] + part2[6][tid] + part2[7][tid];
    HW2[((size_t)k * MS2 + s) * FOUT + tid] = sv;
  }
}

// K6: mu rows for t0,t1 (+b2) via HW2 + reg lookups, then decoder MLP -> sigmoid -> out[k]
__global__ __launch_bounds__(256) void k6_decode(const float* __restrict__ HW2,
                                                 const float* __restrict__ b2,
                                                 const int* __restrict__ cnt1,
                                                 const int* __restrict__ L1src,
                                                 const int* __restrict__ L1sel,
                                                 const int* __restrict__ idx,
                                                 const int* __restrict__ reg,
                                                 const int* __restrict__ deg,
                                                 const float* __restrict__ value,
                                                 const float* __restrict__ Wd,
                                                 const float* __restrict__ bd,
                                                 const float* __restrict__ Wp,
                                                 const float* __restrict__ bp,
                                                 float* __restrict__ out) {
  __shared__ float h[NH + 1];
  __shared__ float o[FHD];
  __shared__ float red[4];
  int k = blockIdx.x;
  int tid = threadIdx.x;
  const int* rk = reg + (size_t)k * NN;
  int n1 = min(cnt1[k], CAP1);
  int tsel = tid >> 7, j = tid & 127;
  int t = idx[2 * k + tsel];
  float dit = dinvf(deg[k * NN + t]);
  int tslot = rk[t] - 1;
  float acc = b2[j] + dit * dit * HW2[((size_t)k * MS2 + tslot) * FOUT + j];
  for (int i = 0; i < n1; i++) {
    if (L1sel[k * CAP1 + i] == tsel) {
      int s = L1src[k * CAP1 + i];
      float dis = dinvf(deg[k * NN + s]);
      int sslot = rk[s] - 1;
      acc += dis * dit * HW2[((size_t)k * MS2 + sslot) * FOUT + j];
    }
  }
  h[tsel * FOUT + j] = acc;
  if (tid < 3) h[2 * FOUT + tid] = value[k * 3 + tid];
  __syncthreads();
  float a2 = bd[tid];
  for (int i = 0; i < NH; i++) a2 += h[i] * Wd[(size_t)i * FHD + tid];
  o[tid] = a2 > 0.f ? a2 : 0.f;
  __syncthreads();
  float r = o[tid] * Wp[tid];
  for (int off2 = 32; off2 > 0; off2 >>= 1) r += __shfl_down(r, off2);
  if ((tid & 63) == 0) red[tid >> 6] = r;
  __syncthreads();
  if (tid == 0) {
    float ssum = red[0] + red[1] + red[2] + red[3] + bp[0];
    out[k] = 1.f / (1.f + expf(-ssum));
  }
}

extern "C" void kernel_launch(void* const* d_in, const int* in_sizes, int n_in,
                              void* d_out, int out_size, void* d_ws, size_t ws_size,
                              hipStream_t stream) {
  const float* x     = (const float*)d_in[0];
  const int*   ei    = (const int*)d_in[1];
  const float* value = (const float*)d_in[2];
  const int*   idx   = (const int*)d_in[3];
  const float* W1    = (const float*)d_in[4];
  const float* b1    = (const float*)d_in[5];
  const float* W2    = (const float*)d_in[6];
  const float* b2    = (const float*)d_in[7];
  const float* Wd    = (const float*)d_in[8];
  const float* bd    = (const float*)d_in[9];
  const float* Wp    = (const float*)d_in[10];
  const float* bp    = (const float*)d_in[11];
  float* out = (float*)d_out;

  char* ws = (char*)d_ws;
  size_t off = 0;
  auto alloc = [&](size_t bytes) -> void* {
    void* p = ws + off;
    off = (off + bytes + 255) & ~(size_t)255;
    return p;
  };
  // --- zeroed region (one kz_zero): reg, deg, bcnt, cnt1, mslots ---
  int* reg   = (int*)alloc((size_t)(2 * KK * NN + KK * MS2 + 2 * KK) * sizeof(int));
  int* deg   = reg + KK * NN;
  int* bcnt  = deg + KK * NN;
  int* cnt1  = bcnt + KK * MS2;
  int* mslots = cnt1 + KK;
  size_t zbytes = (size_t)(2 * KK * NN + KK * MS2 + 2 * KK) * sizeof(int);  // 642080 B, /16 exact
  // --- non-zeroed scratch ---
  int* L1src = (int*)alloc((size_t)KK * CAP1 * sizeof(int));
  int* L1sel = (int*)alloc((size_t)KK * CAP1 * sizeof(int));
  int* slotNode = (int*)alloc((size_t)KK * MS2 * sizeof(int));
  int* bucket = (int*)alloc((size_t)KK * MS2 * BCAP * sizeof(int));
  float* HW2 = (float*)alloc((size_t)KK * MS2 * FOUT * sizeof(float));
  (void)ws_size; (void)in_sizes; (void)n_in; (void)out_size;

  int n4 = (int)(zbytes / 16);
  kz_zero<<<(n4 + 255) / 256, 256, 0, stream>>>((int4*)reg, n4);

  dim3 escan((E4 + 255) / 256, KK);
  k1_scanL1<<<escan, 256, 0, stream>>>(ei, idx, cnt1, L1src, L1sel);
  k2_slots<<<dim3(KK), 256, 0, stream>>>(idx, cnt1, L1src, reg, slotNode, mslots);
  k3_scanL2<<<escan, 256, 0, stream>>>(ei, reg, bcnt, bucket);
  k4_deg<<<escan, 256, 0, stream>>>(ei, reg, deg);
  k5_slotmlp<<<dim3(MS2, KK), 1024, 0, stream>>>(slotNode, mslots, bcnt, bucket, deg,
                                                 x, W1, b1, W2, HW2);
  k6_decode<<<dim3(KK), 256, 0, stream>>>(HW2, b2, cnt1, L1src, L1sel, idx, reg, deg,
                                          value, Wd, bd, Wp, bp, out);
}

// Round 8
// 68.179 us; speedup vs baseline: 4.3017x; 1.0073x over previous
//
#include <hip/hip_runtime.h>
#include <hip/hip_bf16.h>

#define NN 20000
#define EE 320000
#define E4 (EE/4)
#define KK 4
#define FIN 512
#define FHID 256
#define FOUT 128
#define FHD 256
#define NH (2*FOUT+3)   // 259
#define CAP1 1024       // max L1 edges (edges into the 2 targets); expected ~32
#define MS2 128         // max unique slot nodes; expected ~35
#define BCAP 256        // max in-edges per slot node; expected ~45 worst-case

__device__ __forceinline__ float dinvf(int indeg) {
  // reference deg includes the self-loop -> always >= 1
  return rsqrtf((float)(indeg + 1));
}

// KZ: zero the counter/flag region (642 KB).
__global__ __launch_bounds__(256) void kz_zero(int4* __restrict__ p, int n4) {
  int i = blockIdx.x * 256 + threadIdx.x;
  if (i < n4) p[i] = make_int4(0, 0, 0, 0);
}

// K12: scan dst planes; collect L1 edges AND inline CAS-claim slot nodes.
// A claim is idempotent across blocks (one global winner), so no completion
// barrier is needed — unlike round 6's done-counter fusion (TCC-fence disaster).
__global__ __launch_bounds__(256) void k12_scan_claim(const int* __restrict__ ei,
                                                      const int* __restrict__ idx,
                                                      int* __restrict__ cnt1,
                                                      int* __restrict__ L1src,
                                                      int* __restrict__ L1sel,
                                                      int* __restrict__ reg,
                                                      int* __restrict__ slotNode,
                                                      int* __restrict__ mslots) {
  int k = blockIdx.y;
  int* rk = reg + (size_t)k * NN;
  int t0 = idx[2 * k], t1 = idx[2 * k + 1];
  // claim the two target nodes (block 0 only; CAS dedups t0==t1)
  if (blockIdx.x == 0 && threadIdx.x < 2) {
    int node = (threadIdx.x == 0) ? t0 : t1;
    if (atomicCAS(&rk[node], 0, -2) == 0) {
      int s = atomicAdd(&mslots[k], 1);
      if (s < MS2) { slotNode[k * MS2 + s] = node; rk[node] = s + 1; }
    }
  }
  int e4 = blockIdx.x * blockDim.x + threadIdx.x;
  if (e4 >= E4) return;
  const int* srcp = ei + (size_t)k * 2 * EE;
  int4 d4 = ((const int4*)(srcp + EE))[e4];
  int ds[4] = {d4.x, d4.y, d4.z, d4.w};
  #pragma unroll
  for (int c = 0; c < 4; c++) {
    bool h0 = (ds[c] == t0), h1 = (ds[c] == t1);
    if (h0 || h1) {
      int u = srcp[e4 * 4 + c];
      if (h0) {
        int p = atomicAdd(&cnt1[k], 1);
        if (p < CAP1) { L1src[k * CAP1 + p] = u; L1sel[k * CAP1 + p] = 0; }
      }
      if (h1) {
        int p = atomicAdd(&cnt1[k], 1);
        if (p < CAP1) { L1src[k * CAP1 + p] = u; L1sel[k * CAP1 + p] = 1; }
      }
      // inline slot claim for the L1 source
      if (atomicCAS(&rk[u], 0, -2) == 0) {
        int s = atomicAdd(&mslots[k], 1);
        if (s < MS2) { slotNode[k * MS2 + s] = u; rk[u] = s + 1; }
      }
    }
  }
}

// K3: scan; if dst is a slot node, append src to that slot's bucket; flag src as deg-needed
__global__ __launch_bounds__(256) void k3_scanL2(const int* __restrict__ ei,
                                                 int* __restrict__ reg,
                                                 int* __restrict__ bcnt,
                                                 int* __restrict__ bucket) {
  int k = blockIdx.y;
  int e4 = blockIdx.x * blockDim.x + threadIdx.x;
  if (e4 >= E4) return;
  const int* srcp = ei + (size_t)k * 2 * EE;
  int4 d4 = ((const int4*)(srcp + EE))[e4];
  int* rk = reg + (size_t)k * NN;
  int ds[4] = {d4.x, d4.y, d4.z, d4.w};
  #pragma unroll
  for (int c = 0; c < 4; c++) {
    int rv = rk[ds[c]];
    if (rv > 0) {
      int s = rv - 1;
      int u = srcp[e4 * 4 + c];
      int p = atomicAdd(&bcnt[k * MS2 + s], 1);
      if (p < BCAP) bucket[((size_t)k * MS2 + s) * BCAP + p] = u;
      if (rk[u] == 0) rk[u] = -1;  // benign race: both writers store -1
    }
  }
}

// K4: scan; count in-degree only for flagged/registered nodes (~11K atomics total)
__global__ __launch_bounds__(256) void k4_deg(const int* __restrict__ ei,
                                              const int* __restrict__ reg,
                                              int* __restrict__ deg) {
  int k = blockIdx.y;
  int e4 = blockIdx.x * blockDim.x + threadIdx.x;
  if (e4 >= E4) return;
  const int* dstp = ei + (size_t)k * 2 * EE + EE;
  int4 d4 = ((const int4*)dstp)[e4];
  const int* rk = reg + (size_t)k * NN;
  int ds[4] = {d4.x, d4.y, d4.z, d4.w};
  #pragma unroll
  for (int c = 0; c < 4; c++) {
    if (rk[ds[c]] != 0) atomicAdd(&deg[k * NN + ds[c]], 1);
  }
}

// K5: per slot (1024 thr, 16 waves): agg = dn*(dn*x[s] + sum du*x[u]); GEMV1+relu+GEMV2
__global__ __launch_bounds__(1024) void k5_slotmlp(const int* __restrict__ slotNode,
                                                   const int* __restrict__ mslots,
                                                   const int* __restrict__ bcnt,
                                                   const int* __restrict__ bucket,
                                                   const int* __restrict__ deg,
                                                   const float* __restrict__ x,
                                                   const float* __restrict__ W1,
                                                   const float* __restrict__ b1,
                                                   const float* __restrict__ W2,
                                                   float* __restrict__ HW2) {
  __shared__ float aggS[FIN];       // 2 KB
  __shared__ float gtmp[FIN];       // 2 KB
  __shared__ float part[4][FHID];   // 4 KB
  __shared__ float hrow[FHID];      // 1 KB
  __shared__ float part2[8][FOUT];  // 4 KB
  __shared__ int   uS[BCAP];        // 1 KB
  __shared__ float duS[BCAP];       // 1 KB
  int k = blockIdx.y, s = blockIdx.x;
  if (s >= mslots[k]) return;
  int tid = threadIdx.x;
  int node = slotNode[k * MS2 + s];
  int nb = min(bcnt[k * MS2 + s], BCAP);
  const int* bk = bucket + ((size_t)k * MS2 + s) * BCAP;
  for (int e = tid; e < nb; e += 1024) {
    int u = bk[e];
    uS[e] = u;
    duS[e] = dinvf(deg[k * NN + u]);
  }
  __syncthreads();
  float dn = dinvf(deg[k * NN + node]);
  // gather: (half, f) decomposition; x-row loads independent, coalesced
  int f = tid & (FIN - 1), half = tid >> 9;
  float a = (half == 0) ? dn * x[(size_t)node * FIN + f] : 0.f;
  for (int e = half; e < nb; e += 2) a += duS[e] * x[(size_t)uS[e] * FIN + f];
  if (half == 1) gtmp[f] = a;
  __syncthreads();
  if (half == 0) aggS[f] = dn * (a + gtmp[f]);
  __syncthreads();
  // GEMV1: kk split over 4 quarter-blocks
  {
    int q = tid >> 8, j = tid & (FHID - 1);
    float acc = 0.f;
    const float* w1p = W1 + (size_t)(q * 128) * FHID + j;
    const float* ap = aggS + q * 128;
    #pragma unroll 8
    for (int kk = 0; kk < 128; kk++) acc += ap[kk] * w1p[(size_t)kk * FHID];
    part[q][j] = acc;
  }
  __syncthreads();
  if (tid < FHID) {
    float v = part[0][tid] + part[1][tid] + part[2][tid] + part[3][tid] + b1[tid];
    hrow[tid] = v > 0.f ? v : 0.f;
  }
  __syncthreads();
  // GEMV2: kk split over 8 eighth-blocks
  {
    int p = tid >> 7, j = tid & (FOUT - 1);
    float a2 = 0.f;
    const float* w2p = W2 + (size_t)(p * 32) * FOUT + j;
    const float* hp = hrow + p * 32;
    #pragma unroll 8
    for (int kk = 0; kk < 32; kk++) a2 += hp[kk] * w2p[(size_t)kk * FOUT];
    part2[p][j] = a2;
  }
  __syncthreads();
  if (tid < FOUT) {
    float sv = part2[0][tid] + part2[1][tid] + part2[2][tid] + part2[3][tid] +
               part2[4][tid] + part2[5][tid] + part2[6][tid] + part2[7][tid];
    HW2[((size_t)k * MS2 + s) * FOUT + tid] = sv;
  }
}

// K6: mu rows for t0,t1 (+b2) via HW2 + reg lookups, then decoder MLP -> sigmoid -> out[k]
__global__ __launch_bounds__(256) void k6_decode(const float* __restrict__ HW2,
                                                 const float* __restrict__ b2,
                                                 const int* __restrict__ cnt1,
                                                 const int* __restrict__ L1src,
                                                 const int* __restrict__ L1sel,
                                                 const int* __restrict__ idx,
                                                 const int* __restrict__ reg,
                                                 const int* __restrict__ deg,
                                                 const float* __restrict__ value,
                                                 const float* __restrict__ Wd,
                                                 const float* __restrict__ bd,
                                                 const float* __restrict__ Wp,
                                                 const float* __restrict__ bp,
                                                 float* __restrict__ out) {
  __shared__ float h[NH + 1];
  __shared__ float o[FHD];
  __shared__ float red[4];
  int k = blockIdx.x;
  int tid = threadIdx.x;
  const int* rk = reg + (size_t)k * NN;
  int n1 = min(cnt1[k], CAP1);
  int tsel = tid >> 7, j = tid & 127;
  int t = idx[2 * k + tsel];
  float dit = dinvf(deg[k * NN + t]);
  int tslot = rk[t] - 1;
  float acc = b2[j] + dit * dit * HW2[((size_t)k * MS2 + tslot) * FOUT + j];
  for (int i = 0; i < n1; i++) {
    if (L1sel[k * CAP1 + i] == tsel) {
      int s = L1src[k * CAP1 + i];
      float dis = dinvf(deg[k * NN + s]);
      int sslot = rk[s] - 1;
      acc += dis * dit * HW2[((size_t)k * MS2 + sslot) * FOUT + j];
    }
  }
  h[tsel * FOUT + j] = acc;
  if (tid < 3) h[2 * FOUT + tid] = value[k * 3 + tid];
  __syncthreads();
  float a2 = bd[tid];
  for (int i = 0; i < NH; i++) a2 += h[i] * Wd[(size_t)i * FHD + tid];
  o[tid] = a2 > 0.f ? a2 : 0.f;
  __syncthreads();
  float r = o[tid] * Wp[tid];
  for (int off2 = 32; off2 > 0; off2 >>= 1) r += __shfl_down(r, off2);
  if ((tid & 63) == 0) red[tid >> 6] = r;
  __syncthreads();
  if (tid == 0) {
    float ssum = red[0] + red[1] + red[2] + red[3] + bp[0];
    out[k] = 1.f / (1.f + expf(-ssum));
  }
}

extern "C" void kernel_launch(void* const* d_in, const int* in_sizes, int n_in,
                              void* d_out, int out_size, void* d_ws, size_t ws_size,
                              hipStream_t stream) {
  const float* x     = (const float*)d_in[0];
  const int*   ei    = (const int*)d_in[1];
  const float* value = (const float*)d_in[2];
  const int*   idx   = (const int*)d_in[3];
  const float* W1    = (const float*)d_in[4];
  const float* b1    = (const float*)d_in[5];
  const float* W2    = (const float*)d_in[6];
  const float* b2    = (const float*)d_in[7];
  const float* Wd    = (const float*)d_in[8];
  const float* bd    = (const float*)d_in[9];
  const float* Wp    = (const float*)d_in[10];
  const float* bp    = (const float*)d_in[11];
  float* out = (float*)d_out;

  char* ws = (char*)d_ws;
  size_t off = 0;
  auto alloc = [&](size_t bytes) -> void* {
    void* p = ws + off;
    off = (off + bytes + 255) & ~(size_t)255;
    return p;
  };
  // --- zeroed region (one kz_zero): reg, deg, bcnt, cnt1, mslots ---
  int* reg   = (int*)alloc((size_t)(2 * KK * NN + KK * MS2 + 2 * KK) * sizeof(int));
  int* deg   = reg + KK * NN;
  int* bcnt  = deg + KK * NN;
  int* cnt1  = bcnt + KK * MS2;
  int* mslots = cnt1 + KK;
  size_t zbytes = (size_t)(2 * KK * NN + KK * MS2 + 2 * KK) * sizeof(int);  // /16 exact
  // --- non-zeroed scratch ---
  int* L1src = (int*)alloc((size_t)KK * CAP1 * sizeof(int));
  int* L1sel = (int*)alloc((size_t)KK * CAP1 * sizeof(int));
  int* slotNode = (int*)alloc((size_t)KK * MS2 * sizeof(int));
  int* bucket = (int*)alloc((size_t)KK * MS2 * BCAP * sizeof(int));
  float* HW2 = (float*)alloc((size_t)KK * MS2 * FOUT * sizeof(float));
  (void)ws_size; (void)in_sizes; (void)n_in; (void)out_size;

  int n4 = (int)(zbytes / 16);
  kz_zero<<<(n4 + 255) / 256, 256, 0, stream>>>((int4*)reg, n4);

  dim3 escan((E4 + 255) / 256, KK);
  k12_scan_claim<<<escan, 256, 0, stream>>>(ei, idx, cnt1, L1src, L1sel,
                                            reg, slotNode, mslots);
  k3_scanL2<<<escan, 256, 0, stream>>>(ei, reg, bcnt, bucket);
  k4_deg<<<escan, 256, 0, stream>>>(ei, reg, deg);
  k5_slotmlp<<<dim3(MS2, KK), 1024, 0, stream>>>(slotNode, mslots, bcnt, bucket, deg,
                                                 x, W1, b1, W2, HW2);
  k6_decode<<<dim3(KK), 256, 0, stream>>>(HW2, b2, cnt1, L1src, L1sel, idx, reg, deg,
                                          value, Wd, bd, Wp, bp, out);
}